// Round 11
// baseline (151.141 us; speedup 1.0000x reference)
//
#include <hip/hip_runtime.h>

typedef float f32x4 __attribute__((ext_vector_type(4)));
typedef short bf16x8 __attribute__((ext_vector_type(8)));

#define AS1 __attribute__((address_space(1)))
#define AS3 __attribute__((address_space(3)))

__device__ __forceinline__ void gl16(const void* g, void* l) {
  __builtin_amdgcn_global_load_lds((const AS1 unsigned int*)g,
                                   (AS3 unsigned int*)l, 16, 0, 0);
}

__device__ __forceinline__ unsigned short f2bf(float f) {
  unsigned u = __float_as_uint(f);
  u = u + 0x7FFFu + ((u >> 16) & 1u);   // RNE
  return (unsigned short)(u >> 16);
}

// ---------------- K2: style (fused) + modulate + demodulate -> bf16
// layout wm[(n*27+k)*64+o][i], row=128B, 16B chunks XOR-swizzled by (o&7).
__global__ __launch_bounds__(256) void k_wmod(const float* __restrict__ s,
                                              const float* __restrict__ sw,
                                              const float* __restrict__ sb,
                                              const float* __restrict__ weight,
                                              unsigned short* __restrict__ wm) {
  int o = blockIdx.x, n = blockIdx.y, t = threadIdx.x;
  int lane = t & 63, wv = t >> 6;
  // ---- fused style: style[i] = sum_k s[n,k]*sw[i,k] + sb[i]
  __shared__ float st4[64][5];
  __shared__ float st[64];
  {
    int i = t >> 2, part = t & 3;
    const float4* swp = (const float4*)(sw + i * 512 + part * 128);
    const float4* sp4 = (const float4*)(s + n * 512 + part * 128);
    float a = 0.f;
#pragma unroll 8
    for (int kk = 0; kk < 32; ++kk) {
      float4 w4 = swp[kk], s4 = sp4[kk];
      a += w4.x * s4.x + w4.y * s4.y + w4.z * s4.z + w4.w * s4.w;
    }
    st4[i][part] = a;
  }
  __syncthreads();
  if (t < 64) st[t] = st4[t][0] + st4[t][1] + st4[t][2] + st4[t][3] + sb[t];
  __syncthreads();

  const float* wp = weight + o * 1728;   // [i][27]
  float v[7];
  float ss = 0.f;
#pragma unroll
  for (int j = 0; j < 7; ++j) {
    int idx = t + j * 256;
    float w = 0.f;
    if (idx < 1728) {
      int i = idx / 27;
      w = wp[idx] * st[i];
    }
    v[j] = w;
    ss += w * w;
  }
#pragma unroll
  for (int off = 32; off > 0; off >>= 1) ss += __shfl_down(ss, off);
  __shared__ float red[4];
  if (lane == 0) red[wv] = ss;
  __syncthreads();
  float total = red[0] + red[1] + red[2] + red[3];
  float dm = 1.0f / sqrtf(total + 1e-8f);
#pragma unroll
  for (int j = 0; j < 7; ++j) {
    int idx = t + j * 256;
    if (idx < 1728) {
      int i = idx / 27, k = idx - i * 27;
      int g = (n * 27 + k) * 64 + o;
      wm[g * 64 + (((i >> 3) ^ (o & 7)) << 3) + (i & 7)] = f2bf(v[j] * dm);
    }
  }
}

// ---------------- K3: x[N][64][48^3] fp32 -> xT[(n*110592+p)][i] bf16,
// 16B chunks XOR-swizzled by (p&7). 256p x 64i per block; float4 loads,
// coalesced uint4 stores.
__global__ __launch_bounds__(256) void k_xpose(const float* __restrict__ x,
                                               unsigned short* __restrict__ xT) {
  __shared__ unsigned tile[256][33];   // [p][i-pair]
  int n = blockIdx.y;
  int p0 = blockIdx.x * 256;
  int t = threadIdx.x;
  int wv = t >> 6, lane = t & 63;
  const float* xb = x + (size_t)n * 64 * 110592 + p0 + 4 * lane;
#pragma unroll
  for (int c = 0; c < 8; ++c) {
    int i2 = wv + 4 * c;               // i-pair 0..31
    const float4 a = *(const float4*)(xb + (size_t)(2 * i2) * 110592);
    const float4 b = *(const float4*)(xb + (size_t)(2 * i2 + 1) * 110592);
    tile[4 * lane + 0][i2] = (unsigned)f2bf(a.x) | ((unsigned)f2bf(b.x) << 16);
    tile[4 * lane + 1][i2] = (unsigned)f2bf(a.y) | ((unsigned)f2bf(b.y) << 16);
    tile[4 * lane + 2][i2] = (unsigned)f2bf(a.z) | ((unsigned)f2bf(b.z) << 16);
    tile[4 * lane + 3][i2] = (unsigned)f2bf(a.w) | ((unsigned)f2bf(b.w) << 16);
  }
  __syncthreads();
  uint4* dst = (uint4*)xT;
  int sl = t & 7;                      // store slot
#pragma unroll
  for (int pass = 0; pass < 8; ++pass) {
    int p = (t >> 3) + 32 * pass;
    int c = sl ^ (p & 7);              // data chunk living at slot sl
    uint4 u;
    u.x = tile[p][4 * c + 0];
    u.y = tile[p][4 * c + 1];
    u.z = tile[p][4 * c + 2];
    u.w = tile[p][4 * c + 3];
    dst[(size_t)(n * 110592 + p0 + p) * 8 + sl] = u;
  }
}

// ---------------- K4: implicit-GEMM conv. Block: n, 192 flat positions, o=64.
// 4 waves, wave tile 64o x 48p (acc 4m x 3q). LDS = B slab 296x128B (37888)
// + A double-buffer 2x8192 = 54272B total -> 3 blocks/CU = 12 waves/CU.
// A staged one tap ahead via global_load_lds (kills the 12x-redundant L1
// A-stream of the reg version); per-tap {issue A(s+1) -> MFMA(cur) ->
// vmcnt(0) -> s_barrier} (R5 schedule, proven). XCD swizzle (2208 = 8*276).
__global__ __launch_bounds__(256) void k_conv(const unsigned short* __restrict__ xT,
                                              const unsigned short* __restrict__ wm,
                                              const float* __restrict__ bias,
                                              float* __restrict__ out) {
  __shared__ uint4 Bl4[37888 / 16];     // 296 rows x 128B
  __shared__ uint4 Al4[2][8192 / 16];   // A dbuf: 64 rows x 128B each
  char* Bl = (char*)Bl4;

  int bid = blockIdx.x;                       // 0..2207
  int orig = (bid & 7) * 276 + (bid >> 3);    // chunked XCD swizzle (bijective)
  int n = orig / 552;
  int pb = orig - n * 552;
  int p0 = pb * 192;

  int t = threadIdx.x;
  int lane = t & 63, wv = t >> 6;
  int l15 = lane & 15, lhi = lane >> 4;
  f32x4 acc[4][3] = {};

  const char* xb = (const char*)xT + ((size_t)(n * 110592 + p0)) * 128;
  const char* wb = (const char*)wm + (size_t)n * 27 * 8192;

  // per-lane A fragment byte offsets within one 8KB tap tile (swizzle baked
  // into wm layout by k_wmod; gl16 copies the tile linearly into LDS)
  int aoff[8];
#pragma unroll
  for (int m = 0; m < 4; ++m)
#pragma unroll
    for (int ih = 0; ih < 2; ++ih) {
      int orow = m * 16 + l15;
      int c = lhi + ih * 4;
      aoff[m * 2 + ih] = orow * 128 + ((c ^ (orow & 7)) << 4);
    }

  // prologue: issue A-stage for tap 0 into Al[0]
  {
    gl16(wb + wv * 1024 + lane * 16, (char*)Al4[0] + wv * 1024);
    gl16(wb + (wv + 4) * 1024 + lane * 16, (char*)Al4[0] + (wv + 4) * 1024);
  }

#pragma unroll
  for (int kd = 0; kd < 3; ++kd) {
    // stage B slab for this kd (prior kd's readers passed its last tap barrier)
    const char* src = xb + (size_t)kd * (2304 * 128);
    for (int cc = wv; cc < 37; cc += 4)     // 37 chunks = 296 rows
      gl16(src + cc * 1024 + lane * 16, Bl + cc * 1024);
    asm volatile("s_waitcnt vmcnt(0)" ::: "memory");  // B slab + pending A done
    __builtin_amdgcn_s_barrier();
    __builtin_amdgcn_sched_barrier(0);

#pragma unroll
    for (int tap = 0; tap < 9; ++tap) {
      const int s = kd * 9 + tap;     // global tap 0..26
      const int cur = s & 1;
      // issue A-stage for tap s+1 into Al[!cur] (its readers finished before
      // the barrier we just crossed)
      if (s + 1 < 27) {
        const char* ap = wb + (size_t)(s + 1) * 8192;
        gl16(ap + wv * 1024 + lane * 16, (char*)Al4[cur ^ 1] + wv * 1024);
        gl16(ap + (wv + 4) * 1024 + lane * 16, (char*)Al4[cur ^ 1] + (wv + 4) * 1024);
      }
      const int kh = tap / 3, kw = tap - kh * 3;
      const int rbase = wv * 48 + kh * 48 + kw;
      const char* Alc = (const char*)Al4[cur];
#pragma unroll
      for (int ih = 0; ih < 2; ++ih) {
        int c = lhi + ih * 4;
        bf16x8 a[4], b[3];
#pragma unroll
        for (int m = 0; m < 4; ++m)
          a[m] = *(const bf16x8*)(Alc + aoff[m * 2 + ih]);
#pragma unroll
        for (int q = 0; q < 3; ++q) {
          int r = rbase + q * 16 + l15;
          b[q] = *(const bf16x8*)(Bl + r * 128 + ((c ^ (r & 7)) << 4));
        }
        __builtin_amdgcn_s_setprio(1);
#pragma unroll
        for (int m = 0; m < 4; ++m)
#pragma unroll
          for (int q = 0; q < 3; ++q)
            acc[m][q] = __builtin_amdgcn_mfma_f32_16x16x32_bf16(a[m], b[q], acc[m][q], 0, 0, 0);
        __builtin_amdgcn_s_setprio(0);
      }
      // own 2 gl16s (issued at tap start) retired; barrier -> Al[!cur] ready
      asm volatile("s_waitcnt vmcnt(0)" ::: "memory");
      __builtin_amdgcn_s_barrier();
      __builtin_amdgcn_sched_barrier(0);
    }
  }

  float bv[4][4];
#pragma unroll
  for (int m = 0; m < 4; ++m)
#pragma unroll
    for (int r = 0; r < 4; ++r) bv[m][r] = bias[m * 16 + lhi * 4 + r];

  float* ob = out + (size_t)n * 64 * 97336;
#pragma unroll
  for (int q = 0; q < 3; ++q) {
    int p = p0 + wv * 48 + q * 16 + l15;
    int d = p / 2304;
    int rem = p - d * 2304;
    int h = rem / 48;
    int w = rem - h * 48;
    if (h < 46 && w < 46) {  // d < 46 guaranteed: 552*192 = 105984 = 46*2304
      int base = d * 2116 + h * 46 + w;
#pragma unroll
      for (int m = 0; m < 4; ++m)
#pragma unroll
        for (int r = 0; r < 4; ++r) {
          int o = m * 16 + lhi * 4 + r;
          ob[(size_t)o * 97336 + base] = acc[m][q][r] + bv[m][r];
        }
    }
  }
}

extern "C" void kernel_launch(void* const* d_in, const int* in_sizes, int n_in,
                              void* d_out, int out_size, void* d_ws, size_t ws_size,
                              hipStream_t stream) {
  const float* x    = (const float*)d_in[0];
  const float* s    = (const float*)d_in[1];
  const float* sw   = (const float*)d_in[2];
  const float* sb   = (const float*)d_in[3];
  const float* wt   = (const float*)d_in[4];
  const float* bias = (const float*)d_in[5];
  float* out = (float*)d_out;

  // ws layout: [0,1024) unused; [1024, 885760) wm bf16 (4*27*64*64);
  // [885760, +57,225,472) xT bf16 incl. tail pad for shift overreach.
  unsigned short* wm    = (unsigned short*)((char*)d_ws + 1024);
  unsigned short* xT    = (unsigned short*)((char*)d_ws + 1024 + 884736);

  hipLaunchKernelGGL(k_wmod, dim3(64, 4), dim3(256), 0, stream, s, sw, sb, wt, wm);
  hipLaunchKernelGGL(k_xpose, dim3(432, 4), dim3(256), 0, stream, x, xT);
  hipLaunchKernelGGL(k_conv, dim3(2208), dim3(256), 0, stream, xT, wm, bias, out);
}